// Round 9
// baseline (1146.282 us; speedup 1.0000x reference)
//
#include <hip/hip_runtime.h>
#include <hip/hip_bf16.h>
#include <stdint.h>

#define NGRAPH 64
#define NNODE  2048
#define NT     (NGRAPH * NNODE)   // 131072
#define KKEEP  410
#define NEG_SLOPE 0.2f

typedef __attribute__((ext_vector_type(4))) float  f32x4;
typedef __attribute__((ext_vector_type(8))) short  short8v;
typedef __attribute__((ext_vector_type(8))) __bf16 bf16x8;

// ---------------------------------------------------------------------------
// MFMA 16x16x32 bf16 — SFINAE tag-dispatch over the builtin's operand type.
// ---------------------------------------------------------------------------
template <typename A>
__device__ __forceinline__ auto mfma_call(A a, A b, f32x4 c, int)
    -> decltype(__builtin_amdgcn_mfma_f32_16x16x32_bf16(a, b, c, 0, 0, 0)) {
    return __builtin_amdgcn_mfma_f32_16x16x32_bf16(a, b, c, 0, 0, 0);
}
template <typename A>
__device__ __forceinline__ f32x4 mfma_call(A a, A b, f32x4 c, long) {
    return __builtin_amdgcn_mfma_f32_16x16x32_bf16(
        __builtin_bit_cast(bf16x8, a), __builtin_bit_cast(bf16x8, b), c, 0, 0, 0);
}
__device__ __forceinline__ f32x4 MFMA(short8v a, short8v b, f32x4 c) {
    return mfma_call(a, b, c, 0);
}

// split x = hi + lo (bf16 RNE; x-hi exact; bf16 exponent range = f32)
__device__ __forceinline__ void split_bf16(float x, short& hi, short& lo) {
    __bf16 h = (__bf16)x;
    float  hf = (float)h;
    __bf16 l = (__bf16)(x - hf);
    hi = __builtin_bit_cast(short, h);
    lo = __builtin_bit_cast(short, l);
}

__device__ __forceinline__ void gload16(const void* g, void* lds) {
    __builtin_amdgcn_global_load_lds(
        (const __attribute__((address_space(1))) void*)g,
        (__attribute__((address_space(3))) void*)lds,
        16, 0, 0);
}

__device__ __forceinline__ float leaky(float x) {
    return x >= 0.f ? x : NEG_SLOPE * x;
}
__device__ __forceinline__ float dot4(float4 a, float4 b) {
    return a.x * b.x + a.y * b.y + a.z * b.z + a.w * b.w;
}

#define LGKM0() asm volatile("s_waitcnt lgkmcnt(0)" ::: "memory")
#define VMC16() asm volatile("s_waitcnt vmcnt(16)" ::: "memory")
#define VMC0()  asm volatile("s_waitcnt vmcnt(0)"  ::: "memory")

// ---------------------------------------------------------------------------
// Fused GAT-layer GEMM, round-9: PRODUCER/CONSUMER wave specialization.
// Tile 256(M) x 128(N) x 32(K). 512 threads = 8 waves:
//   waves 0-3 CONSUMERS (2x2 of 128x64): ds_read frags + 96 MFMA / step.
//   waves 4-7 PRODUCERS: issueB(t+1) gload_lds, alpha-mix+split+ds_write A(t+1),
//     loadX prefetch (counted vmcnt(16) keeps it in flight across the barrier).
// One s_barrier per K-step (single textual site, all 8 waves, matched count).
// Double-buffered LDS (2 x 48KB): consumer reads buf[t&1] while producers
// write buf[(t+1)&1]; reads of buf[cur] are lgkm-retired before the barrier,
// so overwrite at t+1 is safe. MFMA (consumer) and VALU (producer) pipes run
// concurrently on each SIMD (1+1 waves/SIMD) — no lockstep stall.
// Per-acc accumulation order unchanged from R5-R8 -> h bitwise-identical.
// dout is a per-col-slice partial (2 slices summed downstream).
// ---------------------------------------------------------------------------
#define GBM 256
#define GBN 128
#define BUFSZ  49152   // Ah 16K | Al 16K | Bh 8K | Bl 8K
#define OFF_AL 16384
#define OFF_BH 32768
#define OFF_BL 40960

template <int NVEC, int RELU>
__global__ __launch_bounds__(512, 2)
void gemm_fused(const float* __restrict__ A, const short* __restrict__ Bth,
                const short* __restrict__ Btl, const float* __restrict__ alpha,
                const float* __restrict__ bias, const float* __restrict__ wv,
                float* __restrict__ H, float* __restrict__ dout, int Kcat) {
    extern __shared__ char smem[];
    const int tid  = threadIdx.x;
    const int lane = tid & 63;
    const int w    = tid >> 6;

    // XCD-chunked swizzle: col-pair (bx=0,1) of a row-panel lands on one XCD.
    const int nwg = (int)gridDim.x;                  // 1024, %8==0
    const int wg  = ((int)blockIdx.x & 7) * (nwg >> 3) + ((int)blockIdx.x >> 3);
    const int bx = wg & 1, by = wg >> 1;
    const int R0 = by * GBM, c0 = bx * GBN;

    const int fr = lane & 15, kg = lane >> 4;
    const int nk = Kcat / 32;
    const int Kx = Kcat >> 1;

    // ---------------- producer state (waves 4-7) ----------------
    const int pt    = tid & 255;        // producer thread index
    const int pidx  = w - 4;            // producer wave 0..3
    const int prow0 = pt >> 3;          // + 32*i, i=0..7
    const int pq    = pt & 7;
    int    prow[8];
    float4 aco8[8], xv8[8], xp8[8];

    auto issueB = [&](int t, int buf) {
        char* bh = smem + buf * BUFSZ + OFF_BH;
        char* bl = smem + buf * BUFSZ + OFF_BL;
#pragma unroll
        for (int i = 0; i < 2; ++i) {
            const int rl = pidx * 32 + i * 16 + (lane >> 2);   // 0..127
            const int ks = (lane & 3) ^ ((rl >> 1) & 3);       // pre-swizzled slot
            const size_t go = (size_t)(c0 + rl) * Kcat + (size_t)t * 32 + ks * 8;
            gload16(Bth + go, bh + (pidx * 32 + i * 16) * 64);
            gload16(Btl + go, bl + (pidx * 32 + i * 16) * 64);
        }
    };
    auto loadX = [&](int xblk) {
        const int col = xblk * 32 + pq * 4;
#pragma unroll
        for (int i = 0; i < 8; ++i) {
            const int gr = R0 + prow0 + 32 * i;
            xv8[i] = *reinterpret_cast<const float4*>(&A[(size_t)gr * Kx + col]);
            xp8[i] = *reinterpret_cast<const float4*>(&A[(size_t)prow[i] * Kx + col]);
        }
    };
    auto writeA = [&](int tt, int buf) {
        char* ahp = smem + buf * BUFSZ;
        char* alp = ahp + OFF_AL;
        const int hh = tt & 1;
#pragma unroll
        for (int i = 0; i < 8; ++i) {
            const float ain = hh ? aco8[i].z : aco8[i].x;
            const float asf = hh ? aco8[i].w : aco8[i].y;
            float y[4] = {ain * xp8[i].x + asf * xv8[i].x,
                          ain * xp8[i].y + asf * xv8[i].y,
                          ain * xp8[i].z + asf * xv8[i].z,
                          ain * xp8[i].w + asf * xv8[i].w};
            short4 hv, lv;
            split_bf16(y[0], hv.x, lv.x);
            split_bf16(y[1], hv.y, lv.y);
            split_bf16(y[2], hv.z, lv.z);
            split_bf16(y[3], hv.w, lv.w);
            const int row  = prow0 + 32 * i;
            const int byte = row * 64 + (((pq >> 1) ^ ((row >> 1) & 3)) << 4) + (pq & 1) * 8;
            *reinterpret_cast<short4*>(ahp + byte) = hv;
            *reinterpret_cast<short4*>(alp + byte) = lv;
        }
    };

    // ---------------- consumer state (waves 0-3) ----------------
    const int wm = w >> 1, wn = w & 1;   // valid for w<4
    f32x4 acc[8][4];
#pragma unroll
    for (int m = 0; m < 8; ++m)
#pragma unroll
        for (int n = 0; n < 4; ++n) acc[m][n] = (f32x4)(0.0f);

    // ---------------- prologue: producers stage tile 0 ----------------
    if (w >= 4) {
#pragma unroll
        for (int i = 0; i < 8; ++i) {
            const int gr = R0 + prow0 + 32 * i;
            prow[i] = ((gr & (NNODE - 1)) == 0) ? gr : gr - 1;  // clamp; ain'=0 there
            aco8[i] = *reinterpret_cast<const float4*>(&alpha[(size_t)gr * 4]);
        }
        issueB(0, 0);
        loadX(0);
        writeA(0, 0);       // compiler auto-waits the x loads; drains B(0) too
        LGKM0();
        VMC0();
    }
    __builtin_amdgcn_s_barrier();

    // ---------------- main loop: one barrier per K-step ----------------
    for (int t = 0; t < nk; ++t) {
        const int cur = t & 1, nxt = cur ^ 1;

        if (w < 4) {
            // CONSUMER: frag reads + 96 MFMA (compiler inserts fine lgkmcnt)
            const char* pAh = smem + cur * BUFSZ;
            const char* pAl = pAh + OFF_AL;
            const char* pBh = pAh + OFF_BH;
            const char* pBl = pAh + OFF_BL;

            short8v bhf[4], blf[4];
#pragma unroll
            for (int n = 0; n < 4; ++n) {
                const int rl   = wn * 64 + n * 16 + fr;
                const int byte = rl * 64 + ((kg ^ ((rl >> 1) & 3)) << 4);
                bhf[n] = *reinterpret_cast<const short8v*>(pBh + byte);
                blf[n] = *reinterpret_cast<const short8v*>(pBl + byte);
            }
            __builtin_amdgcn_s_setprio(1);
#pragma unroll
            for (int mp = 0; mp < 4; ++mp) {
                const int m0 = 2 * mp, m1 = m0 + 1;
                const int rl0 = wm * 128 + m0 * 16 + fr;
                const int rl1 = wm * 128 + m1 * 16 + fr;
                const int b0 = rl0 * 64 + ((kg ^ ((rl0 >> 1) & 3)) << 4);
                const int b1 = rl1 * 64 + ((kg ^ ((rl1 >> 1) & 3)) << 4);
                const short8v ah0 = *reinterpret_cast<const short8v*>(pAh + b0);
                const short8v al0 = *reinterpret_cast<const short8v*>(pAl + b0);
                const short8v ah1 = *reinterpret_cast<const short8v*>(pAh + b1);
                const short8v al1 = *reinterpret_cast<const short8v*>(pAl + b1);
#pragma unroll
                for (int n = 0; n < 4; ++n) acc[m0][n] = MFMA(ah0, bhf[n], acc[m0][n]);
#pragma unroll
                for (int n = 0; n < 4; ++n) acc[m1][n] = MFMA(ah1, bhf[n], acc[m1][n]);
#pragma unroll
                for (int n = 0; n < 4; ++n) acc[m0][n] = MFMA(ah0, blf[n], acc[m0][n]);
#pragma unroll
                for (int n = 0; n < 4; ++n) acc[m1][n] = MFMA(ah1, blf[n], acc[m1][n]);
#pragma unroll
                for (int n = 0; n < 4; ++n) acc[m0][n] = MFMA(al0, bhf[n], acc[m0][n]);
#pragma unroll
                for (int n = 0; n < 4; ++n) acc[m1][n] = MFMA(al1, bhf[n], acc[m1][n]);
            }
            __builtin_amdgcn_s_setprio(0);
        } else {
            // PRODUCER: stage tile t+1 into buf[nxt]
            bool dl = false;
            if (t + 1 < nk) {
                issueB(t + 1, nxt);          // 4 gload_lds (oldest vmem this step)
                writeA(t + 1, nxt);          // mix+split+ds_write (auto-waits x regs)
                dl = ((t & 1) == 0) && (t / 2 + 1 < nk / 2);
                if (dl) loadX(t / 2 + 1);    // 16 loads stay in flight past barrier
            }
            LGKM0();                         // ds_writes visible workgroup-wide
            if (dl) VMC16();                 // retire the 4 B DMAs, keep 16 x-loads
            else    VMC0();                  // only B outstanding (L2-warm, cheap)
        }
        __builtin_amdgcn_s_barrier();        // single matched barrier per step
    }

    // ---------------- epilogue: consumers write H + partial dots ----------------
    float* dbuf = (float*)smem;   // buf0 bytes; last step read buf1 (nk even)
    if (w < 4) {
        float bl4[4], wvl[NVEC][4];
#pragma unroll
        for (int n = 0; n < 4; ++n) {
            const int col = c0 + wn * 64 + n * 16 + fr;
            bl4[n] = bias[col];
#pragma unroll
            for (int v = 0; v < NVEC; ++v) wvl[v][n] = wv[v * 256 + col];
        }
#pragma unroll
        for (int m = 0; m < 8; ++m) {
            float pd[4][NVEC];
#pragma unroll
            for (int r = 0; r < 4; ++r)
#pragma unroll
                for (int v = 0; v < NVEC; ++v) pd[r][v] = 0.f;

            const int rowb = wm * 128 + m * 16 + kg * 4;
#pragma unroll
            for (int n = 0; n < 4; ++n) {
                const int col = c0 + wn * 64 + n * 16 + fr;
                float* hp = H + (size_t)(R0 + rowb) * 256 + col;
#pragma unroll
                for (int r = 0; r < 4; ++r) {
                    float hv = acc[m][n][r] + bl4[n];
                    if (RELU) hv = fmaxf(hv, 0.f);
                    hp[(size_t)r * 256] = hv;
#pragma unroll
                    for (int v = 0; v < NVEC; ++v) pd[r][v] += hv * wvl[v][n];
                }
            }
#pragma unroll
            for (int r = 0; r < 4; ++r)
#pragma unroll
                for (int v = 0; v < NVEC; ++v) {
                    float s = pd[r][v];
                    s += __shfl_xor(s, 1);
                    s += __shfl_xor(s, 2);
                    s += __shfl_xor(s, 4);
                    s += __shfl_xor(s, 8);
                    if (fr == 0) dbuf[(rowb + r) * (NVEC * 2) + v * 2 + wn] = s;
                }
        }
    }
    __syncthreads();
    if (tid < 256) {
#pragma unroll
        for (int v = 0; v < NVEC; ++v) {
            const float* d = &dbuf[tid * (NVEC * 2) + v * 2];
            // per-col-slice partial: dout2[row][vec][bx]
            dout[((size_t)(R0 + tid) * NVEC + v) * 2 + bx] = d[0] + d[1];
        }
    }
}

// ---------------------------------------------------------------------------
// prep: Bcat[n][kk] split/transposed, kk = xblk*64 + head*32 + c
// ---------------------------------------------------------------------------
__global__ __launch_bounds__(256)
void build_B(const float* __restrict__ W, short* __restrict__ Bth,
             short* __restrict__ Btl, int Kx) {
    const int Kcat = 2 * Kx;
    const int idx = blockIdx.x * 256 + threadIdx.x;
    if (idx >= 256 * Kcat) return;
    const int n = idx / Kcat, kk = idx % Kcat;
    const int xblk = kk >> 6, rem = kk & 63, head = rem >> 5, c = rem & 31;
    const int k = xblk * 32 + c;
    short h, l;
    split_bf16(W[(size_t)k * 512 + head * 256 + n], h, l);
    Bth[idx] = h;
    Btl[idx] = l;
}

// wvec[vec][k] = sum_c W[k][head*256+c] * att[head][c];  vec: 0,1=src h0,h1; 2,3=dst
__global__ __launch_bounds__(256)
void build_wvec(const float* __restrict__ W, const float* __restrict__ att_src,
                const float* __restrict__ att_dst, float* __restrict__ wvec, int K) {
    const int idx = blockIdx.x * 256 + threadIdx.x;
    if (idx >= 4 * K) return;
    const int vec = idx / K, k = idx % K;
    const int head = vec & 1;
    const float* att = (vec < 2) ? att_src : att_dst;
    float s = 0.f;
    for (int c = 0; c < 256; ++c)
        s += W[(size_t)k * 512 + head * 256 + c] * att[head * 256 + c];
    wvec[idx] = s;
}

__global__ __launch_bounds__(256)
void pack_sc(const float* __restrict__ pW_root, const float* __restrict__ pW_rel,
             float* __restrict__ wsc) {
    const int t = blockIdx.x * 256 + threadIdx.x;
    if (t < 256) wsc[t] = pW_root[t];
    else if (t < 512) wsc[t] = pW_rel[t - 256];
}

// ---------------------------------------------------------------------------
// Layer-1 raw dots from x only (one wave per node): {s0,s1,d0,d1}.
// ---------------------------------------------------------------------------
__global__ __launch_bounds__(256)
void dots_x(const float* __restrict__ x, const float* __restrict__ wvec,
            float* __restrict__ rawd) {
    const int v = blockIdx.x * 4 + (threadIdx.x >> 6);
    const int lane = threadIdx.x & 63;

    const float4 xa = *reinterpret_cast<const float4*>(&x[(size_t)v * 512 + lane * 4]);
    const float4 xb = *reinterpret_cast<const float4*>(&x[(size_t)v * 512 + 256 + lane * 4]);
    const float4 s0a = *reinterpret_cast<const float4*>(&wvec[0 * 512 + lane * 4]);
    const float4 s0b = *reinterpret_cast<const float4*>(&wvec[0 * 512 + 256 + lane * 4]);
    const float4 s1a = *reinterpret_cast<const float4*>(&wvec[1 * 512 + lane * 4]);
    const float4 s1b = *reinterpret_cast<const float4*>(&wvec[1 * 512 + 256 + lane * 4]);
    const float4 d0a = *reinterpret_cast<const float4*>(&wvec[2 * 512 + lane * 4]);
    const float4 d0b = *reinterpret_cast<const float4*>(&wvec[2 * 512 + 256 + lane * 4]);
    const float4 d1a = *reinterpret_cast<const float4*>(&wvec[3 * 512 + lane * 4]);
    const float4 d1b = *reinterpret_cast<const float4*>(&wvec[3 * 512 + 256 + lane * 4]);

    float sv0 = dot4(xa, s0a) + dot4(xb, s0b);
    float sv1 = dot4(xa, s1a) + dot4(xb, s1b);
    float dv0 = dot4(xa, d0a) + dot4(xb, d0b);
    float dv1 = dot4(xa, d1a) + dot4(xb, d1b);
#pragma unroll
    for (int off = 32; off; off >>= 1) {
        sv0 += __shfl_xor(sv0, off); sv1 += __shfl_xor(sv1, off);
        dv0 += __shfl_xor(dv0, off); dv1 += __shfl_xor(dv1, off);
    }
    if (lane == 0) {
        float4 o = {sv0, sv1, dv0, dv1};
        *reinterpret_cast<float4*>(&rawd[(size_t)v * 4]) = o;
    }
}

// ---------------------------------------------------------------------------
// alpha from raw dots; W = #partial slices per value (1 = dots_x, 2 = GEMM dout)
// ---------------------------------------------------------------------------
template <int W>
__global__ __launch_bounds__(256)
void alpha_from_dots(const float* __restrict__ rawd, float* __restrict__ alph) {
    const int v = blockIdx.x * 256 + threadIdx.x;
    if (v >= NT) return;
    const int j = v & (NNODE - 1);

    auto rd = [&](int node, int vec) -> float {
        const float* p = &rawd[((size_t)node * 4 + vec) * W];
        float s = p[0];
        if (W == 2) s += p[1];
        return s;
    };

    float4 o = {0.f, 0.5f, 0.f, 0.5f};
    if (j > 0) {
        {
            const float ein = leaky(rd(v - 1, 0) + rd(v, 2));
            const float esf = leaky(rd(v, 0) + rd(v, 2));
            const float m = fmaxf(ein, esf);
            const float win = expf(ein - m), wsf = expf(esf - m);
            const float den = win + wsf + 1e-16f;
            o.x = 0.5f * win / den; o.y = 0.5f * wsf / den;
        }
        {
            const float ein = leaky(rd(v - 1, 1) + rd(v, 3));
            const float esf = leaky(rd(v, 1) + rd(v, 3));
            const float m = fmaxf(ein, esf);
            const float win = expf(ein - m), wsf = expf(esf - m);
            const float den = win + wsf + 1e-16f;
            o.z = 0.5f * win / den; o.w = 0.5f * wsf / den;
        }
    }
    *reinterpret_cast<float4*>(&alph[(size_t)v * 4]) = o;
}

// ---------------------------------------------------------------------------
// Per-graph top-K + gated mean pool + classifier.
// rawsc layout [node][vec][bx]: score[i] = (q[0]+q[1]) + pb + (i>0 ? prev(q[2]+q[3]) : 0)
// ---------------------------------------------------------------------------
__global__ __launch_bounds__(1024)
void topk_pool(const float* __restrict__ rawsc, const float* __restrict__ h,
               const float* __restrict__ cls_W, const float* __restrict__ cls_b,
               const float* __restrict__ pb, float* __restrict__ out) {
    __shared__ unsigned long long keys[NNODE];
    __shared__ float sc[NNODE];
    __shared__ float partial[4][256];
    __shared__ float red[8];

    const int b = blockIdx.x;
    const int tid = threadIdx.x;
    const float pbv = pb[0];

    for (int i = tid; i < NNODE; i += 1024) {
        const float* q = &rawsc[((size_t)b * NNODE + i) * 4];
        float v = q[0] + q[1] + pbv;
        if (i > 0) {
            const float* qp = &rawsc[((size_t)b * NNODE + i - 1) * 4];
            v += qp[2] + qp[3];
        }
        sc[i] = v;
        unsigned u = __float_as_uint(v);
        u = (u & 0x80000000u) ? ~u : (u | 0x80000000u);
        keys[i] = ((unsigned long long)(~u) << 32) | (unsigned)i;
    }
    __syncthreads();

    for (int k = 2; k <= NNODE; k <<= 1) {
        for (int jj = k >> 1; jj > 0; jj >>= 1) {
            int i = ((tid & ~(jj - 1)) << 1) | (tid & (jj - 1));
            int ixj = i | jj;
            unsigned long long a = keys[i], c = keys[ixj];
            bool up = ((i & k) == 0);
            if ((a > c) == up) { keys[i] = c; keys[ixj] = a; }
            __syncthreads();
        }
    }

    const int g = tid >> 8;
    const int c = tid & 255;
    float acc = 0.f;
    for (int kk = g; kk < KKEEP; kk += 4) {
        int idx = (int)(keys[kk] & 0xffffffffu);
        float gate = tanhf(sc[idx]);
        acc += h[((size_t)b * NNODE + idx) * 256 + c] * gate;
    }
    partial[g][c] = acc;
    __syncthreads();

    if (tid < 256) {
        float pooled = (partial[0][tid] + partial[1][tid] +
                        partial[2][tid] + partial[3][tid]) / (float)KKEEP;
        float p0 = pooled * cls_W[tid * 2 + 0];
        float p1 = pooled * cls_W[tid * 2 + 1];
#pragma unroll
        for (int off = 32; off; off >>= 1) {
            p0 += __shfl_down(p0, off);
            p1 += __shfl_down(p1, off);
        }
        if ((tid & 63) == 0) {
            red[(tid >> 6) * 2 + 0] = p0;
            red[(tid >> 6) * 2 + 1] = p1;
        }
    }
    __syncthreads();
    if (tid == 0) {
        out[b * 2 + 0] = red[0] + red[2] + red[4] + red[6] + cls_b[0];
        out[b * 2 + 1] = red[1] + red[3] + red[5] + red[7] + cls_b[1];
    }
}

// ---------------------------------------------------------------------------

extern "C" void kernel_launch(void* const* d_in, const int* in_sizes, int n_in,
                              void* d_out, int out_size, void* d_ws, size_t ws_size,
                              hipStream_t stream) {
    const float* x        = (const float*)d_in[0];
    const float* W1       = (const float*)d_in[1];
    const float* att_src1 = (const float*)d_in[2];
    const float* att_dst1 = (const float*)d_in[3];
    const float* b1       = (const float*)d_in[4];
    const float* W2       = (const float*)d_in[5];
    const float* att_src2 = (const float*)d_in[6];
    const float* att_dst2 = (const float*)d_in[7];
    const float* b2       = (const float*)d_in[8];
    const float* pW_root  = (const float*)d_in[9];
    const float* pW_rel   = (const float*)d_in[10];
    const float* pb       = (const float*)d_in[11];
    const float* cls_W    = (const float*)d_in[12];
    const float* cls_b    = (const float*)d_in[13];
    float* out = (float*)d_out;

    // workspace (~283 MB):
    float* h1     = (float*)d_ws;               // NT*256 f32
    float* h2     = h1 + (size_t)NT * 256;      // NT*256 f32
    float* alpha1 = h2 + (size_t)NT * 256;      // NT*4
    float* rawd1  = alpha1 + (size_t)NT * 4;    // NT*4   (dots_x, W=1)
    float* rawd2  = rawd1 + (size_t)NT * 4;     // NT*8   (L1 dout, NVEC=4, 2 slices)
    float* alpha2 = rawd2 + (size_t)NT * 8;     // NT*4
    float* rawsc  = alpha2 + (size_t)NT * 4;    // NT*4   (L2 dout, NVEC=2, 2 slices)
    short* B1h    = (short*)(rawsc + (size_t)NT * 4);  // 256*1024
    short* B1l    = B1h + 256 * 1024;
    short* B2h    = B1l + 256 * 1024;           // 256*512
    short* B2l    = B2h + 256 * 512;
    float* wvec1  = (float*)(B2l + 256 * 512);  // 4*512
    float* wvec2  = wvec1 + 4 * 512;            // 4*256
    float* wsc    = wvec2 + 4 * 256;            // 512

    // ---- prep (tiny)
    build_wvec<<<(4 * 512 + 255) / 256, 256, 0, stream>>>(W1, att_src1, att_dst1, wvec1, 512);
    build_wvec<<<(4 * 256 + 255) / 256, 256, 0, stream>>>(W2, att_src2, att_dst2, wvec2, 256);
    build_B<<<(256 * 1024) / 256, 256, 0, stream>>>(W1, B1h, B1l, 512);
    build_B<<<(256 * 512) / 256, 256, 0, stream>>>(W2, B2h, B2l, 256);
    pack_sc<<<2, 256, 0, stream>>>(pW_root, pW_rel, wsc);

    const int gemm_grid = (NT / GBM) * (256 / GBN);   // 512 * 2 = 1024
    const size_t lds_bytes = 2 * BUFSZ;               // 96 KiB

    // ---- layer 1: raw dots from x, alpha, producer/consumer fused GEMM -> h1
    dots_x<<<NT / 4, 256, 0, stream>>>(x, wvec1, rawd1);
    alpha_from_dots<1><<<NT / 256, 256, 0, stream>>>(rawd1, alpha1);
    gemm_fused<4, 1><<<gemm_grid, 512, lds_bytes, stream>>>(
        x, B1h, B1l, alpha1, b1, wvec2, h1, rawd2, 1024);

    // ---- layer 2: alpha2 from L1 epilogue dots (2 slices), fused GEMM -> h2
    alpha_from_dots<2><<<NT / 256, 256, 0, stream>>>(rawd2, alpha2);
    gemm_fused<2, 0><<<gemm_grid, 512, lds_bytes, stream>>>(
        h1, B2h, B2l, alpha2, b2, wsc, h2, rawsc, 512);

    // ---- SAGPool top-k + gated mean pool + classifier
    topk_pool<<<NGRAPH, 1024, 0, stream>>>(rawsc, h2, cls_W, cls_b, pb, out);
}

// Round 10
// 443.252 us; speedup vs baseline: 2.5861x; 2.5861x over previous
//
#include <hip/hip_runtime.h>
#include <hip/hip_bf16.h>
#include <stdint.h>

#define NGRAPH 64
#define NNODE  2048
#define NT     (NGRAPH * NNODE)   // 131072
#define KKEEP  410
#define NEG_SLOPE 0.2f

typedef __attribute__((ext_vector_type(4))) float  f32x4;
typedef __attribute__((ext_vector_type(8))) short  short8v;
typedef __attribute__((ext_vector_type(8))) __bf16 bf16x8;

// ---------------------------------------------------------------------------
// MFMA 16x16x32 bf16 — SFINAE tag-dispatch over the builtin's operand type.
// ---------------------------------------------------------------------------
template <typename A>
__device__ __forceinline__ auto mfma_call(A a, A b, f32x4 c, int)
    -> decltype(__builtin_amdgcn_mfma_f32_16x16x32_bf16(a, b, c, 0, 0, 0)) {
    return __builtin_amdgcn_mfma_f32_16x16x32_bf16(a, b, c, 0, 0, 0);
}
template <typename A>
__device__ __forceinline__ f32x4 mfma_call(A a, A b, f32x4 c, long) {
    return __builtin_amdgcn_mfma_f32_16x16x32_bf16(
        __builtin_bit_cast(bf16x8, a), __builtin_bit_cast(bf16x8, b), c, 0, 0, 0);
}
__device__ __forceinline__ f32x4 MFMA(short8v a, short8v b, f32x4 c) {
    return mfma_call(a, b, c, 0);
}

// split x = hi + lo (bf16 RNE; x-hi exact; bf16 exponent range = f32)
__device__ __forceinline__ void split_bf16(float x, short& hi, short& lo) {
    __bf16 h = (__bf16)x;
    float  hf = (float)h;
    __bf16 l = (__bf16)(x - hf);
    hi = __builtin_bit_cast(short, h);
    lo = __builtin_bit_cast(short, l);
}

__device__ __forceinline__ void gload16(const void* g, void* lds) {
    __builtin_amdgcn_global_load_lds(
        (const __attribute__((address_space(1))) void*)g,
        (__attribute__((address_space(3))) void*)lds,
        16, 0, 0);
}

__device__ __forceinline__ float leaky(float x) {
    return x >= 0.f ? x : NEG_SLOPE * x;
}
__device__ __forceinline__ float dot4(float4 a, float4 b) {
    return a.x * b.x + a.y * b.y + a.z * b.z + a.w * b.w;
}

#define LGKM0() asm volatile("s_waitcnt lgkmcnt(0)" ::: "memory")
#define VMC8()  asm volatile("s_waitcnt vmcnt(8)"  ::: "memory")
#define VMC0()  asm volatile("s_waitcnt vmcnt(0)"  ::: "memory")

// ---------------------------------------------------------------------------
// Fused GAT-layer GEMM — R8 structure VERBATIM (benched 249us, MfmaUtil 36%),
// only NVEC widened to 8: the epilogue's per-row dots now also produce the
// layer-2 attention dots AND the SAGPool root/rel functionals, which lets the
// entire layer-2 GEMM be replaced by pool-then-project (linearity).
// ---------------------------------------------------------------------------
#define GBM 256
#define GBK 32
#define LDS_BUF 65536
#define OFF_AL  16384
#define OFF_BH  32768
#define OFF_BL  49152

template <int NVEC, int RELU>
__global__ __launch_bounds__(512, 2)
void gemm_fused(const float* __restrict__ A, const short* __restrict__ Bth,
                const short* __restrict__ Btl, const float* __restrict__ alpha,
                const float* __restrict__ bias, const float* __restrict__ wv,
                float* __restrict__ H, float* __restrict__ dout, int Kcat) {
    extern __shared__ char smem[];
    const int tid  = threadIdx.x;
    const int lane = tid & 63;
    const int w    = tid >> 6;
    const int wm = w >> 2, wn = w & 3;
    const int R0 = (int)blockIdx.x * GBM;
    const int fr = lane & 15, kg = lane >> 4;
    const int nk = Kcat / GBK;
    const int Kx = Kcat >> 1;

    f32x4 acc[8][4];
#pragma unroll
    for (int m = 0; m < 8; ++m)
#pragma unroll
        for (int n = 0; n < 4; ++n) acc[m][n] = (f32x4)(0.0f);

    const int arow0 = tid >> 3;
    const int aq    = tid & 7;

    int    prow[4];
    float4 aco[4];
    float4 xv[4], xp[4];
#pragma unroll
    for (int i = 0; i < 4; ++i) {
        const int gr = R0 + arow0 + 64 * i;
        prow[i] = ((gr & (NNODE - 1)) == 0) ? gr : gr - 1;   // clamp; ain'=0 there
        aco[i]  = *reinterpret_cast<const float4*>(&alpha[(size_t)gr * 4]);
    }

    auto issueB = [&](int t, int buf) {
        char* bh = smem + buf * LDS_BUF + OFF_BH;
        char* bl = smem + buf * LDS_BUF + OFF_BL;
#pragma unroll
        for (int i = 0; i < 2; ++i) {
            const int rl = w * 32 + i * 16 + (lane >> 2);
            const int ks = (lane & 3) ^ ((rl >> 1) & 3);
            const size_t go = (size_t)rl * Kcat + (size_t)t * GBK + ks * 8;
            gload16(Bth + go, bh + (w * 32 + i * 16) * 64);
            gload16(Btl + go, bl + (w * 32 + i * 16) * 64);
        }
    };
    auto loadX = [&](int xblk) {
        const int col = xblk * 32 + aq * 4;
#pragma unroll
        for (int i = 0; i < 4; ++i) {
            const int gr = R0 + arow0 + 64 * i;
            xv[i] = *reinterpret_cast<const float4*>(&A[(size_t)gr * Kx + col]);
            xp[i] = *reinterpret_cast<const float4*>(&A[(size_t)prow[i] * Kx + col]);
        }
    };
    auto writeA = [&](int tt, int buf) {
        char* ahp = smem + buf * LDS_BUF;
        char* alp = ahp + OFF_AL;
        const int hh = tt & 1;
#pragma unroll
        for (int i = 0; i < 4; ++i) {
            const float ain = hh ? aco[i].z : aco[i].x;
            const float asf = hh ? aco[i].w : aco[i].y;
            float y[4] = {ain * xp[i].x + asf * xv[i].x,
                          ain * xp[i].y + asf * xv[i].y,
                          ain * xp[i].z + asf * xv[i].z,
                          ain * xp[i].w + asf * xv[i].w};
            short4 hv, lv;
            split_bf16(y[0], hv.x, lv.x);
            split_bf16(y[1], hv.y, lv.y);
            split_bf16(y[2], hv.z, lv.z);
            split_bf16(y[3], hv.w, lv.w);
            const int row  = arow0 + 64 * i;
            const int byte = (row * 64 + (((aq >> 1) ^ ((row >> 1) & 3)) << 4) + (aq & 1) * 8);
            *reinterpret_cast<short4*>(ahp + byte) = hv;
            *reinterpret_cast<short4*>(alp + byte) = lv;
        }
    };

    // prologue: stage tile 0 (xblk0/head0) into buf0
    issueB(0, 0);
    loadX(0);
    writeA(0, 0);
    LGKM0();
    VMC0();
    __builtin_amdgcn_s_barrier();

    for (int t = 0; t < nk; ++t) {
        const int cur = t & 1, nxt = cur ^ 1;
        const char* pAh = smem + cur * LDS_BUF;
        const char* pAl = pAh + OFF_AL;
        const char* pBh = pAh + OFF_BH;
        const char* pBl = pAh + OFF_BL;

        short8v bhf[4], blf[4];
#pragma unroll
        for (int mp = 0; mp < 4; ++mp) {
            if (mp == 0) {
#pragma unroll
                for (int n = 0; n < 4; ++n) {
                    const int rl   = wn * 64 + n * 16 + fr;
                    const int byte = rl * 64 + ((kg ^ ((rl >> 1) & 3)) << 4);
                    bhf[n] = *reinterpret_cast<const short8v*>(pBh + byte);
                    blf[n] = *reinterpret_cast<const short8v*>(pBl + byte);
                }
                if (t + 1 < nk) issueB(t + 1, nxt);
            }
            const int m0 = 2 * mp, m1 = m0 + 1;
            const int rl0 = wm * 128 + m0 * 16 + fr;
            const int rl1 = wm * 128 + m1 * 16 + fr;
            const int b0 = rl0 * 64 + ((kg ^ ((rl0 >> 1) & 3)) << 4);
            const int b1 = rl1 * 64 + ((kg ^ ((rl1 >> 1) & 3)) << 4);
            const short8v ah0 = *reinterpret_cast<const short8v*>(pAh + b0);
            const short8v al0 = *reinterpret_cast<const short8v*>(pAl + b0);
            const short8v ah1 = *reinterpret_cast<const short8v*>(pAh + b1);
            const short8v al1 = *reinterpret_cast<const short8v*>(pAl + b1);

            __builtin_amdgcn_s_barrier();
            LGKM0();
            __builtin_amdgcn_s_setprio(1);
#pragma unroll
            for (int n = 0; n < 4; ++n) acc[m0][n] = MFMA(ah0, bhf[n], acc[m0][n]);
#pragma unroll
            for (int n = 0; n < 4; ++n) acc[m1][n] = MFMA(ah1, bhf[n], acc[m1][n]);
#pragma unroll
            for (int n = 0; n < 4; ++n) acc[m0][n] = MFMA(ah0, blf[n], acc[m0][n]);
#pragma unroll
            for (int n = 0; n < 4; ++n) acc[m1][n] = MFMA(ah1, blf[n], acc[m1][n]);
#pragma unroll
            for (int n = 0; n < 4; ++n) acc[m0][n] = MFMA(al0, bhf[n], acc[m0][n]);
#pragma unroll
            for (int n = 0; n < 4; ++n) acc[m1][n] = MFMA(al1, bhf[n], acc[m1][n]);
            __builtin_amdgcn_s_setprio(0);
        }

        const bool dl = ((t & 1) == 0) && (t / 2 + 1 < nk / 2);
        if (t + 1 < nk) {
            writeA(t + 1, nxt);
            if (dl) loadX(t / 2 + 1);
        }
        LGKM0();
        if (t + 1 < nk) {
            if (dl) VMC8();
            else    VMC0();
        }
        __builtin_amdgcn_s_barrier();
    }

    // ---- epilogue: bias(+relu) -> H ; per-row partial dots with wv -> dout
    float bl4[4], wvl[NVEC][4];
#pragma unroll
    for (int n = 0; n < 4; ++n) {
        const int col = wn * 64 + n * 16 + fr;
        bl4[n] = bias[col];
#pragma unroll
        for (int v = 0; v < NVEC; ++v) wvl[v][n] = wv[v * 256 + col];
    }
    float* dbuf = (float*)smem;

#pragma unroll
    for (int m = 0; m < 8; ++m) {
        float pd[4][NVEC];
#pragma unroll
        for (int r = 0; r < 4; ++r)
#pragma unroll
            for (int v = 0; v < NVEC; ++v) pd[r][v] = 0.f;

        const int rowb = wm * 128 + m * 16 + kg * 4;
#pragma unroll
        for (int n = 0; n < 4; ++n) {
            const int col = wn * 64 + n * 16 + fr;
            float* hp = H + (size_t)(R0 + rowb) * 256 + col;
#pragma unroll
            for (int r = 0; r < 4; ++r) {
                float hv = acc[m][n][r] + bl4[n];
                if (RELU) hv = fmaxf(hv, 0.f);
                hp[(size_t)r * 256] = hv;
#pragma unroll
                for (int v = 0; v < NVEC; ++v) pd[r][v] += hv * wvl[v][n];
            }
        }
#pragma unroll
        for (int r = 0; r < 4; ++r)
#pragma unroll
            for (int v = 0; v < NVEC; ++v) {
                float s = pd[r][v];
                s += __shfl_xor(s, 1);
                s += __shfl_xor(s, 2);
                s += __shfl_xor(s, 4);
                s += __shfl_xor(s, 8);
                if (fr == 0) dbuf[(rowb + r) * (NVEC * 4) + v * 4 + wn] = s;
            }
    }
    __syncthreads();
    if (tid < 256) {
#pragma unroll
        for (int v = 0; v < NVEC; ++v) {
            const float* d = &dbuf[tid * (NVEC * 4) + v * 4];
            dout[(size_t)(R0 + tid) * NVEC + v] = d[0] + d[1] + d[2] + d[3];
        }
    }
}

// ---------------------------------------------------------------------------
// prep: B1[n][kk] split/transposed, kk = xblk*64 + head*32 + c  (layer-1 only)
// ---------------------------------------------------------------------------
__global__ __launch_bounds__(256)
void build_B(const float* __restrict__ W, short* __restrict__ Bth,
             short* __restrict__ Btl, int Kx) {
    const int Kcat = 2 * Kx;
    const int idx = blockIdx.x * 256 + threadIdx.x;
    if (idx >= 256 * Kcat) return;
    const int n = idx / Kcat, kk = idx % Kcat;
    const int xblk = kk >> 6, rem = kk & 63, head = rem >> 5, c = rem & 31;
    const int k = xblk * 32 + c;
    short h, l;
    split_bf16(W[(size_t)k * 512 + head * 256 + n], h, l);
    Bth[idx] = h;
    Btl[idx] = l;
}

// wvec1[vec][k] = sum_c W1[k][head*256+c] * att[head][c] (layer-1 dots, 4 vecs)
__global__ __launch_bounds__(256)
void build_wvec(const float* __restrict__ W, const float* __restrict__ att_src,
                const float* __restrict__ att_dst, float* __restrict__ wvec, int K) {
    const int idx = blockIdx.x * 256 + threadIdx.x;
    if (idx >= 4 * K) return;
    const int vec = idx / K, k = idx % K;
    const int head = vec & 1;
    const float* att = (vec < 2) ? att_src : att_dst;
    float s = 0.f;
    for (int c = 0; c < 256; ++c)
        s += W[(size_t)k * 512 + head * 256 + c] * att[head * 256 + c];
    wvec[idx] = s;
}

// wv2[vec][k], k over h1 cols (256): vec 0/1 = W2_h@att_src2, 2/3 = W2_h@att_dst2,
// 4/5 = W2_h@pW_root, 6/7 = W2_h@pW_rel   (h = vec&1)
__global__ __launch_bounds__(256)
void build_wvec8(const float* __restrict__ W2, const float* __restrict__ att_src,
                 const float* __restrict__ att_dst, const float* __restrict__ pW_root,
                 const float* __restrict__ pW_rel, float* __restrict__ wv2) {
    const int idx = blockIdx.x * 256 + threadIdx.x;
    if (idx >= 8 * 256) return;
    const int vec = idx >> 8, k = idx & 255;
    const int head = vec & 1;
    float s = 0.f;
    if (vec < 2)      for (int c = 0; c < 256; ++c) s += W2[(size_t)k * 512 + head * 256 + c] * att_src[head * 256 + c];
    else if (vec < 4) for (int c = 0; c < 256; ++c) s += W2[(size_t)k * 512 + head * 256 + c] * att_dst[head * 256 + c];
    else if (vec < 6) for (int c = 0; c < 256; ++c) s += W2[(size_t)k * 512 + head * 256 + c] * pW_root[c];
    else              for (int c = 0; c < 256; ++c) s += W2[(size_t)k * 512 + head * 256 + c] * pW_rel[c];
    wv2[idx] = s;
}

// consts = { b2.pW_root, b2.pW_rel }
__global__ __launch_bounds__(256)
void build_consts(const float* __restrict__ b2, const float* __restrict__ pW_root,
                  const float* __restrict__ pW_rel, float* __restrict__ consts) {
    const int t = threadIdx.x;
    float r = b2[t] * pW_root[t];
    float l = b2[t] * pW_rel[t];
#pragma unroll
    for (int off = 32; off; off >>= 1) { r += __shfl_xor(r, off); l += __shfl_xor(l, off); }
    __shared__ float red[8];
    if ((t & 63) == 0) { red[(t >> 6) * 2] = r; red[(t >> 6) * 2 + 1] = l; }
    __syncthreads();
    if (t == 0) {
        consts[0] = red[0] + red[2] + red[4] + red[6];
        consts[1] = red[1] + red[3] + red[5] + red[7];
    }
}

// ---------------------------------------------------------------------------
// Layer-1 raw dots from x (one wave per node): {s0,s1,d0,d1}
// ---------------------------------------------------------------------------
__global__ __launch_bounds__(256)
void dots_x(const float* __restrict__ x, const float* __restrict__ wvec,
            float* __restrict__ rawd) {
    const int v = blockIdx.x * 4 + (threadIdx.x >> 6);
    const int lane = threadIdx.x & 63;

    const float4 xa = *reinterpret_cast<const float4*>(&x[(size_t)v * 512 + lane * 4]);
    const float4 xb = *reinterpret_cast<const float4*>(&x[(size_t)v * 512 + 256 + lane * 4]);
    const float4 s0a = *reinterpret_cast<const float4*>(&wvec[0 * 512 + lane * 4]);
    const float4 s0b = *reinterpret_cast<const float4*>(&wvec[0 * 512 + 256 + lane * 4]);
    const float4 s1a = *reinterpret_cast<const float4*>(&wvec[1 * 512 + lane * 4]);
    const float4 s1b = *reinterpret_cast<const float4*>(&wvec[1 * 512 + 256 + lane * 4]);
    const float4 d0a = *reinterpret_cast<const float4*>(&wvec[2 * 512 + lane * 4]);
    const float4 d0b = *reinterpret_cast<const float4*>(&wvec[2 * 512 + 256 + lane * 4]);
    const float4 d1a = *reinterpret_cast<const float4*>(&wvec[3 * 512 + lane * 4]);
    const float4 d1b = *reinterpret_cast<const float4*>(&wvec[3 * 512 + 256 + lane * 4]);

    float sv0 = dot4(xa, s0a) + dot4(xb, s0b);
    float sv1 = dot4(xa, s1a) + dot4(xb, s1b);
    float dv0 = dot4(xa, d0a) + dot4(xb, d0b);
    float dv1 = dot4(xa, d1a) + dot4(xb, d1b);
#pragma unroll
    for (int off = 32; off; off >>= 1) {
        sv0 += __shfl_xor(sv0, off); sv1 += __shfl_xor(sv1, off);
        dv0 += __shfl_xor(dv0, off); dv1 += __shfl_xor(dv1, off);
    }
    if (lane == 0) {
        float4 o = {sv0, sv1, dv0, dv1};
        *reinterpret_cast<float4*>(&rawd[(size_t)v * 4]) = o;
    }
}

// ---------------------------------------------------------------------------
// alpha1 from rawd1 {s0,s1,d0,d1} (stride 4)
// ---------------------------------------------------------------------------
__global__ __launch_bounds__(256)
void alpha_from_dots(const float* __restrict__ rawd, float* __restrict__ alph) {
    const int v = blockIdx.x * 256 + threadIdx.x;
    if (v >= NT) return;
    const int j = v & (NNODE - 1);
    float4 o = {0.f, 0.5f, 0.f, 0.5f};
    if (j > 0) {
        const float4 dv = *reinterpret_cast<const float4*>(&rawd[(size_t)v * 4]);
        const float4 dp = *reinterpret_cast<const float4*>(&rawd[(size_t)(v - 1) * 4]);
        {
            const float ein = leaky(dp.x + dv.z), esf = leaky(dv.x + dv.z);
            const float m = fmaxf(ein, esf);
            const float win = expf(ein - m), wsf = expf(esf - m);
            const float den = win + wsf + 1e-16f;
            o.x = 0.5f * win / den; o.y = 0.5f * wsf / den;
        }
        {
            const float ein = leaky(dp.y + dv.w), esf = leaky(dv.y + dv.w);
            const float m = fmaxf(ein, esf);
            const float win = expf(ein - m), wsf = expf(esf - m);
            const float den = win + wsf + 1e-16f;
            o.z = 0.5f * win / den; o.w = 0.5f * wsf / den;
        }
    }
    *reinterpret_cast<float4*>(&alph[(size_t)v * 4]) = o;
}

// ---------------------------------------------------------------------------
// Layer-2 alpha + SAGPool score, all from rawd2 (NT x 8 per-node dots):
//   vec 0-3: att dots (src0,src1,dst0,dst1) -> alpha2
//   vec 4,5: droot_h = h1[v].(W2_h@pW_root); 6,7: drel_h
// score[v] = h2[v].pW_root + [j>0] h2[v-1].pW_rel + pb, expanded via linearity.
// ---------------------------------------------------------------------------
__device__ __forceinline__ float4 alpha_of(const float* __restrict__ rawd, int v, int j) {
    float4 o = {0.f, 0.5f, 0.f, 0.5f};
    if (j > 0) {
        const float* dv = &rawd[(size_t)v * 8];
        const float* dp = &rawd[(size_t)(v - 1) * 8];
        {
            const float ein = leaky(dp[0] + dv[2]), esf = leaky(dv[0] + dv[2]);
            const float m = fmaxf(ein, esf);
            const float win = expf(ein - m), wsf = expf(esf - m);
            const float den = win + wsf + 1e-16f;
            o.x = 0.5f * win / den; o.y = 0.5f * wsf / den;
        }
        {
            const float ein = leaky(dp[1] + dv[3]), esf = leaky(dv[1] + dv[3]);
            const float m = fmaxf(ein, esf);
            const float win = expf(ein - m), wsf = expf(esf - m);
            const float den = win + wsf + 1e-16f;
            o.z = 0.5f * win / den; o.w = 0.5f * wsf / den;
        }
    }
    return o;
}

__global__ __launch_bounds__(256)
void score_alpha(const float* __restrict__ rawd, const float* __restrict__ consts,
                 const float* __restrict__ pb, float* __restrict__ alph,
                 float* __restrict__ score) {
    const int v = blockIdx.x * 256 + threadIdx.x;
    if (v >= NT) return;
    const int j = v & (NNODE - 1);

    const float4 o = alpha_of(rawd, v, j);
    *reinterpret_cast<float4*>(&alph[(size_t)v * 4]) = o;

    // own-root: h2[v].pW_root = sum_h ain_h'*droot_h[v-1] + asf_h'*droot_h[v] + b2root
    const int vm1 = (j > 0) ? v - 1 : v;   // o.x=o.z=0 when j==0
    float s = consts[0] + pb[0];
    s += o.x * rawd[(size_t)vm1 * 8 + 4] + o.y * rawd[(size_t)v * 8 + 4];
    s += o.z * rawd[(size_t)vm1 * 8 + 5] + o.w * rawd[(size_t)v * 8 + 5];

    if (j > 0) {
        // rel: h2[v-1].pW_rel (alpha of node v-1; its own j' = j-1)
        const float4 op = alpha_of(rawd, v - 1, j - 1);
        const int vm2 = (j > 1) ? v - 2 : v - 1;   // op.x=op.z=0 when j==1
        s += consts[1];
        s += op.x * rawd[(size_t)vm2 * 8 + 6] + op.y * rawd[(size_t)(v - 1) * 8 + 6];
        s += op.z * rawd[(size_t)vm2 * 8 + 7] + op.w * rawd[(size_t)(v - 1) * 8 + 7];
    }
    score[v] = s;
}

// ---------------------------------------------------------------------------
// Per-graph top-K + gated MIX-pool + mini-GEMM (pool@W2) + classifier.
// pooled[b] = ( (sum_sel gate*mix2(h1))@W2cat + (sum gate)*b2 ) / K
// out[b]    = pooled @ cls_W + cls_b
// ---------------------------------------------------------------------------
__global__ __launch_bounds__(1024)
void topk_pool(const float* __restrict__ score, const float* __restrict__ h1,
               const float* __restrict__ alpha2, const float* __restrict__ W2,
               const float* __restrict__ b2, const float* __restrict__ cls_W,
               const float* __restrict__ cls_b, float* __restrict__ out) {
    __shared__ unsigned long long keys[NNODE];
    __shared__ float sc[NNODE];
    __shared__ float pmix[4][512];   // [group][head*256 + c]
    __shared__ float gpart[4];
    __shared__ float red[8];

    const int b = blockIdx.x;
    const int tid = threadIdx.x;

    for (int i = tid; i < NNODE; i += 1024) {
        float v = score[(size_t)b * NNODE + i];
        sc[i] = v;
        unsigned u = __float_as_uint(v);
        u = (u & 0x80000000u) ? ~u : (u | 0x80000000u);
        keys[i] = ((unsigned long long)(~u) << 32) | (unsigned)i;
    }
    __syncthreads();

    for (int k = 2; k <= NNODE; k <<= 1) {
        for (int jj = k >> 1; jj > 0; jj >>= 1) {
            int i = ((tid & ~(jj - 1)) << 1) | (tid & (jj - 1));
            int ixj = i | jj;
            unsigned long long a = keys[i], c = keys[ixj];
            bool up = ((i & k) == 0);
            if ((a > c) == up) { keys[i] = c; keys[ixj] = a; }
            __syncthreads();
        }
    }

    // gated mix accumulation over top-K (P = sum gate*mix, G = sum gate)
    const int g = tid >> 8;
    const int c = tid & 255;
    float a0 = 0.f, a1 = 0.f, gs = 0.f;
    for (int kk = g; kk < KKEEP; kk += 4) {
        const int idx  = (int)(keys[kk] & 0xffffffffu);
        const float gate = tanhf(sc[idx]);
        const size_t gidx = (size_t)b * NNODE + idx;
        const size_t pidx = (idx == 0) ? gidx : gidx - 1;   // ain'=0 at j==0
        const float4 al = *reinterpret_cast<const float4*>(&alpha2[gidx * 4]);
        const float hv = h1[gidx * 256 + c];
        const float hp = h1[pidx * 256 + c];
        a0 += gate * (al.x * hp + al.y * hv);
        a1 += gate * (al.z * hp + al.w * hv);
        if (c == 0) gs += gate;
    }
    pmix[g][c]       = a0;
    pmix[g][256 + c] = a1;
    if (c == 0) gpart[g] = gs;
    __syncthreads();

    // reduce groups -> P[512] (in pmix[0]) and G
    if (tid < 512) pmix[0][tid] += pmix[1][tid] + pmix[2][tid] + pmix[3][tid];
    __syncthreads();

    // mini-GEMM: pooled[n] = (sum_c P0[c]*W2[c][n] + P1[c]*W2[c][256+n] + G*b2[n]) / K
    if (tid < 256) {
        const float G = gpart[0] + gpart[1] + gpart[2] + gpart[3];
        const int n = tid;
        float s = 0.f;
        for (int cc = 0; cc < 256; ++cc) {
            const float* wrow = &W2[(size_t)cc * 512];
            s += pmix[0][cc] * wrow[n] + pmix[0][256 + cc] * wrow[256 + n];
        }
        const float pooled = (s + G * b2[n]) * (1.f / (float)KKEEP);
        float p0 = pooled * cls_W[n * 2 + 0];
        float p1 = pooled * cls_W[n * 2 + 1];
#pragma unroll
        for (int off = 32; off; off >>= 1) {
            p0 += __shfl_down(p0, off);
            p1 += __shfl_down(p1, off);
        }
        if ((n & 63) == 0) {
            red[(n >> 6) * 2 + 0] = p0;
            red[(n >> 6) * 2 + 1] = p1;
        }
    }
    __syncthreads();
    if (tid == 0) {
        out[b * 2 + 0] = red[0] + red[2] + red[4] + red[6] + cls_b[0];
        out[b * 2 + 1] = red[1] + red[3] + red[5] + red[7] + cls_b[1];
    }
}

// ---------------------------------------------------------------------------

extern "C" void kernel_launch(void* const* d_in, const int* in_sizes, int n_in,
                              void* d_out, int out_size, void* d_ws, size_t ws_size,
                              hipStream_t stream) {
    const float* x        = (const float*)d_in[0];
    const float* W1       = (const float*)d_in[1];
    const float* att_src1 = (const float*)d_in[2];
    const float* att_dst1 = (const float*)d_in[3];
    const float* b1       = (const float*)d_in[4];
    const float* W2       = (const float*)d_in[5];
    const float* att_src2 = (const float*)d_in[6];
    const float* att_dst2 = (const float*)d_in[7];
    const float* b2       = (const float*)d_in[8];
    const float* pW_root  = (const float*)d_in[9];
    const float* pW_rel   = (const float*)d_in[10];
    const float* pb       = (const float*)d_in[11];
    const float* cls_W    = (const float*)d_in[12];
    const float* cls_b    = (const float*)d_in[13];
    float* out = (float*)d_out;

    // workspace (~150 MB; h2 / B2 / L2-GEMM eliminated):
    float* h1     = (float*)d_ws;               // NT*256 f32
    float* alpha1 = h1 + (size_t)NT * 256;      // NT*4
    float* rawd1  = alpha1 + (size_t)NT * 4;    // NT*4
    float* rawd2  = rawd1 + (size_t)NT * 4;     // NT*8
    float* alpha2 = rawd2 + (size_t)NT * 8;     // NT*4
    float* score  = alpha2 + (size_t)NT * 4;    // NT
    short* B1h    = (short*)(score + NT);       // 256*1024
    short* B1l    = B1h + 256 * 1024;
    float* wvec1  = (float*)(B1l + 256 * 1024); // 4*512
    float* wv2    = wvec1 + 4 * 512;            // 8*256
    float* consts = wv2 + 8 * 256;              // 2

    // ---- prep (tiny)
    build_wvec<<<(4 * 512 + 255) / 256, 256, 0, stream>>>(W1, att_src1, att_dst1, wvec1, 512);
    build_wvec8<<<8, 256, 0, stream>>>(W2, att_src2, att_dst2, pW_root, pW_rel, wv2);
    build_B<<<(256 * 1024) / 256, 256, 0, stream>>>(W1, B1h, B1l, 512);
    build_consts<<<1, 256, 0, stream>>>(b2, pW_root, pW_rel, consts);

    // ---- layer 1: dots from x, alpha1, fused mix+GEMM -> h1 (+8 dots/node)
    dots_x<<<NT / 4, 256, 0, stream>>>(x, wvec1, rawd1);
    alpha_from_dots<<<NT / 256, 256, 0, stream>>>(rawd1, alpha1);
    gemm_fused<8, 1><<<NT / GBM, 512, 131072, stream>>>(
        x, B1h, B1l, alpha1, b1, wv2, h1, rawd2, 1024);

    // ---- layer 2 collapsed: alpha2+score from per-node dots (no GEMM)
    score_alpha<<<NT / 256, 256, 0, stream>>>(rawd2, consts, pb, alpha2, score);

    // ---- SAGPool top-k + gated mix-pool + pool@W2 + classifier
    topk_pool<<<NGRAPH, 1024, 0, stream>>>(score, h1, alpha2, W2, b2, cls_W, cls_b, out);
}

// Round 11
// 416.093 us; speedup vs baseline: 2.7549x; 1.0653x over previous
//
#include <hip/hip_runtime.h>
#include <hip/hip_bf16.h>
#include <stdint.h>

#define NGRAPH 64
#define NNODE  2048
#define NT     (NGRAPH * NNODE)   // 131072
#define KKEEP  410
#define NEG_SLOPE 0.2f

typedef __attribute__((ext_vector_type(4))) float  f32x4;
typedef __attribute__((ext_vector_type(8))) short  short8v;
typedef __attribute__((ext_vector_type(8))) __bf16 bf16x8;

// ---------------------------------------------------------------------------
// MFMA 16x16x32 bf16 — SFINAE tag-dispatch over the builtin's operand type.
// ---------------------------------------------------------------------------
template <typename A>
__device__ __forceinline__ auto mfma_call(A a, A b, f32x4 c, int)
    -> decltype(__builtin_amdgcn_mfma_f32_16x16x32_bf16(a, b, c, 0, 0, 0)) {
    return __builtin_amdgcn_mfma_f32_16x16x32_bf16(a, b, c, 0, 0, 0);
}
template <typename A>
__device__ __forceinline__ f32x4 mfma_call(A a, A b, f32x4 c, long) {
    return __builtin_amdgcn_mfma_f32_16x16x32_bf16(
        __builtin_bit_cast(bf16x8, a), __builtin_bit_cast(bf16x8, b), c, 0, 0, 0);
}
__device__ __forceinline__ f32x4 MFMA(short8v a, short8v b, f32x4 c) {
    return mfma_call(a, b, c, 0);
}

// split x = hi + lo (bf16 RNE; x-hi exact; bf16 exponent range = f32)
__device__ __forceinline__ void split_bf16(float x, short& hi, short& lo) {
    __bf16 h = (__bf16)x;
    float  hf = (float)h;
    __bf16 l = (__bf16)(x - hf);
    hi = __builtin_bit_cast(short, h);
    lo = __builtin_bit_cast(short, l);
}

__device__ __forceinline__ void gload16(const void* g, void* lds) {
    __builtin_amdgcn_global_load_lds(
        (const __attribute__((address_space(1))) void*)g,
        (__attribute__((address_space(3))) void*)lds,
        16, 0, 0);
}

__device__ __forceinline__ float leaky(float x) {
    return x >= 0.f ? x : NEG_SLOPE * x;
}
__device__ __forceinline__ float dot4(float4 a, float4 b) {
    return a.x * b.x + a.y * b.y + a.z * b.z + a.w * b.w;
}

#define LGKM0() asm volatile("s_waitcnt lgkmcnt(0)" ::: "memory")
#define VMC8()  asm volatile("s_waitcnt vmcnt(8)"  ::: "memory")
#define VMC0()  asm volatile("s_waitcnt vmcnt(0)"  ::: "memory")

// ---------------------------------------------------------------------------
// Fused GAT-layer GEMM — R8 K-loop VERBATIM (benched 249us, MfmaUtil 36%).
// Round-11: epilogue stripped to bias+ReLU+store only. All per-node dots
// (layer-2 attention + SAGPool functionals) moved to the dots_h pass, which
// reads L3-resident h1 — removes 1024 FMA + 1024 shuffles + 128B-stride
// dbuf bank conflicts per thread from this kernel. K-loop unchanged ->
// h1 bitwise-identical to rounds 8-10.
// ---------------------------------------------------------------------------
#define GBM 256
#define GBK 32
#define LDS_BUF 65536
#define OFF_AL  16384
#define OFF_BH  32768
#define OFF_BL  49152

__global__ __launch_bounds__(512, 2)
void gemm_fused(const float* __restrict__ A, const short* __restrict__ Bth,
                const short* __restrict__ Btl, const float* __restrict__ alpha,
                const float* __restrict__ bias, float* __restrict__ H, int Kcat) {
    extern __shared__ char smem[];
    const int tid  = threadIdx.x;
    const int lane = tid & 63;
    const int w    = tid >> 6;
    const int wm = w >> 2, wn = w & 3;
    const int R0 = (int)blockIdx.x * GBM;
    const int fr = lane & 15, kg = lane >> 4;
    const int nk = Kcat / GBK;
    const int Kx = Kcat >> 1;

    f32x4 acc[8][4];
#pragma unroll
    for (int m = 0; m < 8; ++m)
#pragma unroll
        for (int n = 0; n < 4; ++n) acc[m][n] = (f32x4)(0.0f);

    const int arow0 = tid >> 3;
    const int aq    = tid & 7;

    int    prow[4];
    float4 aco[4];
    float4 xv[4], xp[4];
#pragma unroll
    for (int i = 0; i < 4; ++i) {
        const int gr = R0 + arow0 + 64 * i;
        prow[i] = ((gr & (NNODE - 1)) == 0) ? gr : gr - 1;   // clamp; ain'=0 there
        aco[i]  = *reinterpret_cast<const float4*>(&alpha[(size_t)gr * 4]);
    }

    auto issueB = [&](int t, int buf) {
        char* bh = smem + buf * LDS_BUF + OFF_BH;
        char* bl = smem + buf * LDS_BUF + OFF_BL;
#pragma unroll
        for (int i = 0; i < 2; ++i) {
            const int rl = w * 32 + i * 16 + (lane >> 2);
            const int ks = (lane & 3) ^ ((rl >> 1) & 3);
            const size_t go = (size_t)rl * Kcat + (size_t)t * GBK + ks * 8;
            gload16(Bth + go, bh + (w * 32 + i * 16) * 64);
            gload16(Btl + go, bl + (w * 32 + i * 16) * 64);
        }
    };
    auto loadX = [&](int xblk) {
        const int col = xblk * 32 + aq * 4;
#pragma unroll
        for (int i = 0; i < 4; ++i) {
            const int gr = R0 + arow0 + 64 * i;
            xv[i] = *reinterpret_cast<const float4*>(&A[(size_t)gr * Kx + col]);
            xp[i] = *reinterpret_cast<const float4*>(&A[(size_t)prow[i] * Kx + col]);
        }
    };
    auto writeA = [&](int tt, int buf) {
        char* ahp = smem + buf * LDS_BUF;
        char* alp = ahp + OFF_AL;
        const int hh = tt & 1;
#pragma unroll
        for (int i = 0; i < 4; ++i) {
            const float ain = hh ? aco[i].z : aco[i].x;
            const float asf = hh ? aco[i].w : aco[i].y;
            float y[4] = {ain * xp[i].x + asf * xv[i].x,
                          ain * xp[i].y + asf * xv[i].y,
                          ain * xp[i].z + asf * xv[i].z,
                          ain * xp[i].w + asf * xv[i].w};
            short4 hv, lv;
            split_bf16(y[0], hv.x, lv.x);
            split_bf16(y[1], hv.y, lv.y);
            split_bf16(y[2], hv.z, lv.z);
            split_bf16(y[3], hv.w, lv.w);
            const int row  = arow0 + 64 * i;
            const int byte = (row * 64 + (((aq >> 1) ^ ((row >> 1) & 3)) << 4) + (aq & 1) * 8);
            *reinterpret_cast<short4*>(ahp + byte) = hv;
            *reinterpret_cast<short4*>(alp + byte) = lv;
        }
    };

    // prologue: stage tile 0 (xblk0/head0) into buf0
    issueB(0, 0);
    loadX(0);
    writeA(0, 0);
    LGKM0();
    VMC0();
    __builtin_amdgcn_s_barrier();

    for (int t = 0; t < nk; ++t) {
        const int cur = t & 1, nxt = cur ^ 1;
        const char* pAh = smem + cur * LDS_BUF;
        const char* pAl = pAh + OFF_AL;
        const char* pBh = pAh + OFF_BH;
        const char* pBl = pAh + OFF_BL;

        short8v bhf[4], blf[4];
#pragma unroll
        for (int mp = 0; mp < 4; ++mp) {
            if (mp == 0) {
#pragma unroll
                for (int n = 0; n < 4; ++n) {
                    const int rl   = wn * 64 + n * 16 + fr;
                    const int byte = rl * 64 + ((kg ^ ((rl >> 1) & 3)) << 4);
                    bhf[n] = *reinterpret_cast<const short8v*>(pBh + byte);
                    blf[n] = *reinterpret_cast<const short8v*>(pBl + byte);
                }
                if (t + 1 < nk) issueB(t + 1, nxt);
            }
            const int m0 = 2 * mp, m1 = m0 + 1;
            const int rl0 = wm * 128 + m0 * 16 + fr;
            const int rl1 = wm * 128 + m1 * 16 + fr;
            const int b0 = rl0 * 64 + ((kg ^ ((rl0 >> 1) & 3)) << 4);
            const int b1 = rl1 * 64 + ((kg ^ ((rl1 >> 1) & 3)) << 4);
            const short8v ah0 = *reinterpret_cast<const short8v*>(pAh + b0);
            const short8v al0 = *reinterpret_cast<const short8v*>(pAl + b0);
            const short8v ah1 = *reinterpret_cast<const short8v*>(pAh + b1);
            const short8v al1 = *reinterpret_cast<const short8v*>(pAl + b1);

            __builtin_amdgcn_s_barrier();
            LGKM0();
            __builtin_amdgcn_s_setprio(1);
#pragma unroll
            for (int n = 0; n < 4; ++n) acc[m0][n] = MFMA(ah0, bhf[n], acc[m0][n]);
#pragma unroll
            for (int n = 0; n < 4; ++n) acc[m1][n] = MFMA(ah1, bhf[n], acc[m1][n]);
#pragma unroll
            for (int n = 0; n < 4; ++n) acc[m0][n] = MFMA(ah0, blf[n], acc[m0][n]);
#pragma unroll
            for (int n = 0; n < 4; ++n) acc[m1][n] = MFMA(ah1, blf[n], acc[m1][n]);
#pragma unroll
            for (int n = 0; n < 4; ++n) acc[m0][n] = MFMA(al0, bhf[n], acc[m0][n]);
#pragma unroll
            for (int n = 0; n < 4; ++n) acc[m1][n] = MFMA(al1, bhf[n], acc[m1][n]);
            __builtin_amdgcn_s_setprio(0);
        }

        const bool dl = ((t & 1) == 0) && (t / 2 + 1 < nk / 2);
        if (t + 1 < nk) {
            writeA(t + 1, nxt);
            if (dl) loadX(t / 2 + 1);
        }
        LGKM0();
        if (t + 1 < nk) {
            if (dl) VMC8();
            else    VMC0();
        }
        __builtin_amdgcn_s_barrier();
    }

    // ---- epilogue: bias + ReLU -> H (pure register->global, no LDS)
    float bl4[4];
#pragma unroll
    for (int n = 0; n < 4; ++n) bl4[n] = bias[wn * 64 + n * 16 + fr];

#pragma unroll
    for (int m = 0; m < 8; ++m) {
        const int rowb = wm * 128 + m * 16 + kg * 4;
#pragma unroll
        for (int n = 0; n < 4; ++n) {
            const int col = wn * 64 + n * 16 + fr;
            float* hp = H + (size_t)(R0 + rowb) * 256 + col;
#pragma unroll
            for (int r = 0; r < 4; ++r)
                hp[(size_t)r * 256] = fmaxf(acc[m][n][r] + bl4[n], 0.f);
        }
    }
}

// ---------------------------------------------------------------------------
// prep: B1[n][kk] split/transposed, kk = xblk*64 + head*32 + c  (layer-1 only)
// ---------------------------------------------------------------------------
__global__ __launch_bounds__(256)
void build_B(const float* __restrict__ W, short* __restrict__ Bth,
             short* __restrict__ Btl, int Kx) {
    const int Kcat = 2 * Kx;
    const int idx = blockIdx.x * 256 + threadIdx.x;
    if (idx >= 256 * Kcat) return;
    const int n = idx / Kcat, kk = idx % Kcat;
    const int xblk = kk >> 6, rem = kk & 63, head = rem >> 5, c = rem & 31;
    const int k = xblk * 32 + c;
    short h, l;
    split_bf16(W[(size_t)k * 512 + head * 256 + n], h, l);
    Bth[idx] = h;
    Btl[idx] = l;
}

// ---------------------------------------------------------------------------
// merged small prep: blocks 0-7 -> wvec1 (4 vecs x 512), blocks 8-15 -> wv2
// (8 vecs x 256), block 16 -> consts {b2.pW_root, b2.pW_rel}.
// ---------------------------------------------------------------------------
__global__ __launch_bounds__(256)
void build_misc(const float* __restrict__ W1, const float* __restrict__ as1,
                const float* __restrict__ ad1, const float* __restrict__ W2,
                const float* __restrict__ as2, const float* __restrict__ ad2,
                const float* __restrict__ pW_root, const float* __restrict__ pW_rel,
                const float* __restrict__ b2, float* __restrict__ wvec1,
                float* __restrict__ wv2, float* __restrict__ consts) {
    const int bid = blockIdx.x;
    const int t = threadIdx.x;
    if (bid < 8) {
        // wvec1[vec][k] = sum_c W1[k][head*256+c]*att1[head][c], vec:0,1 src;2,3 dst
        const int idx = bid * 256 + t;          // < 2048
        const int vec = idx / 512, k = idx % 512;
        const int head = vec & 1;
        const float* att = (vec < 2) ? as1 : ad1;
        float s = 0.f;
        for (int c = 0; c < 256; ++c)
            s += W1[(size_t)k * 512 + head * 256 + c] * att[head * 256 + c];
        wvec1[idx] = s;
    } else if (bid < 16) {
        // wv2[vec][k]: 0/1 W2h@as2, 2/3 W2h@ad2, 4/5 W2h@pW_root, 6/7 W2h@pW_rel
        const int idx = (bid - 8) * 256 + t;    // < 2048
        const int vec = idx >> 8, k = idx & 255;
        const int head = vec & 1;
        float s = 0.f;
        if (vec < 2)      for (int c = 0; c < 256; ++c) s += W2[(size_t)k * 512 + head * 256 + c] * as2[head * 256 + c];
        else if (vec < 4) for (int c = 0; c < 256; ++c) s += W2[(size_t)k * 512 + head * 256 + c] * ad2[head * 256 + c];
        else if (vec < 6) for (int c = 0; c < 256; ++c) s += W2[(size_t)k * 512 + head * 256 + c] * pW_root[c];
        else              for (int c = 0; c < 256; ++c) s += W2[(size_t)k * 512 + head * 256 + c] * pW_rel[c];
        wv2[idx] = s;
    } else {
        float r = b2[t] * pW_root[t];
        float l = b2[t] * pW_rel[t];
#pragma unroll
        for (int off = 32; off; off >>= 1) { r += __shfl_xor(r, off); l += __shfl_xor(l, off); }
        __shared__ float red[8];
        if ((t & 63) == 0) { red[(t >> 6) * 2] = r; red[(t >> 6) * 2 + 1] = l; }
        __syncthreads();
        if (t == 0) {
            consts[0] = red[0] + red[2] + red[4] + red[6];
            consts[1] = red[1] + red[3] + red[5] + red[7];
        }
    }
}

// ---------------------------------------------------------------------------
// Layer-1 raw dots from x (one wave per node): {s0,s1,d0,d1}
// ---------------------------------------------------------------------------
__global__ __launch_bounds__(256)
void dots_x(const float* __restrict__ x, const float* __restrict__ wvec,
            float* __restrict__ rawd) {
    const int v = blockIdx.x * 4 + (threadIdx.x >> 6);
    const int lane = threadIdx.x & 63;

    const float4 xa = *reinterpret_cast<const float4*>(&x[(size_t)v * 512 + lane * 4]);
    const float4 xb = *reinterpret_cast<const float4*>(&x[(size_t)v * 512 + 256 + lane * 4]);
    const float4 s0a = *reinterpret_cast<const float4*>(&wvec[0 * 512 + lane * 4]);
    const float4 s0b = *reinterpret_cast<const float4*>(&wvec[0 * 512 + 256 + lane * 4]);
    const float4 s1a = *reinterpret_cast<const float4*>(&wvec[1 * 512 + lane * 4]);
    const float4 s1b = *reinterpret_cast<const float4*>(&wvec[1 * 512 + 256 + lane * 4]);
    const float4 d0a = *reinterpret_cast<const float4*>(&wvec[2 * 512 + lane * 4]);
    const float4 d0b = *reinterpret_cast<const float4*>(&wvec[2 * 512 + 256 + lane * 4]);
    const float4 d1a = *reinterpret_cast<const float4*>(&wvec[3 * 512 + lane * 4]);
    const float4 d1b = *reinterpret_cast<const float4*>(&wvec[3 * 512 + 256 + lane * 4]);

    float sv0 = dot4(xa, s0a) + dot4(xb, s0b);
    float sv1 = dot4(xa, s1a) + dot4(xb, s1b);
    float dv0 = dot4(xa, d0a) + dot4(xb, d0b);
    float dv1 = dot4(xa, d1a) + dot4(xb, d1b);
#pragma unroll
    for (int off = 32; off; off >>= 1) {
        sv0 += __shfl_xor(sv0, off); sv1 += __shfl_xor(sv1, off);
        dv0 += __shfl_xor(dv0, off); dv1 += __shfl_xor(dv1, off);
    }
    if (lane == 0) {
        float4 o = {sv0, sv1, dv0, dv1};
        *reinterpret_cast<float4*>(&rawd[(size_t)v * 4]) = o;
    }
}

// ---------------------------------------------------------------------------
// alpha1 from rawd1 {s0,s1,d0,d1} (stride 4)
// ---------------------------------------------------------------------------
__global__ __launch_bounds__(256)
void alpha_from_dots(const float* __restrict__ rawd, float* __restrict__ alph) {
    const int v = blockIdx.x * 256 + threadIdx.x;
    if (v >= NT) return;
    const int j = v & (NNODE - 1);
    float4 o = {0.f, 0.5f, 0.f, 0.5f};
    if (j > 0) {
        const float4 dv = *reinterpret_cast<const float4*>(&rawd[(size_t)v * 4]);
        const float4 dp = *reinterpret_cast<const float4*>(&rawd[(size_t)(v - 1) * 4]);
        {
            const float ein = leaky(dp.x + dv.z), esf = leaky(dv.x + dv.z);
            const float m = fmaxf(ein, esf);
            const float win = expf(ein - m), wsf = expf(esf - m);
            const float den = win + wsf + 1e-16f;
            o.x = 0.5f * win / den; o.y = 0.5f * wsf / den;
        }
        {
            const float ein = leaky(dp.y + dv.w), esf = leaky(dv.y + dv.w);
            const float m = fmaxf(ein, esf);
            const float win = expf(ein - m), wsf = expf(esf - m);
            const float den = win + wsf + 1e-16f;
            o.z = 0.5f * win / den; o.w = 0.5f * wsf / den;
        }
    }
    *reinterpret_cast<float4*>(&alph[(size_t)v * 4]) = o;
}

// ---------------------------------------------------------------------------
// Per-node dots of h1 against the 8 wv2 functionals (one wave per node).
// h1 is L3-resident (134MB) -> memory-bound ~20us. Replaces the GEMM-epilogue
// dout path (which cost ~40us of VALU + bank conflicts inside the GEMM).
// ---------------------------------------------------------------------------
__global__ __launch_bounds__(256)
void dots_h(const float* __restrict__ h1, const float* __restrict__ wv2,
            float* __restrict__ rawd) {
    const int v = blockIdx.x * 4 + (threadIdx.x >> 6);
    const int lane = threadIdx.x & 63;

    const float4 hv = *reinterpret_cast<const float4*>(&h1[(size_t)v * 256 + lane * 4]);
    float d[8];
#pragma unroll
    for (int vec = 0; vec < 8; ++vec) {
        const float4 wq = *reinterpret_cast<const float4*>(&wv2[vec * 256 + lane * 4]);
        d[vec] = dot4(hv, wq);
    }
#pragma unroll
    for (int off = 32; off; off >>= 1)
#pragma unroll
        for (int vec = 0; vec < 8; ++vec) d[vec] += __shfl_xor(d[vec], off);
    if (lane == 0) {
        float4 o0 = {d[0], d[1], d[2], d[3]};
        float4 o1 = {d[4], d[5], d[6], d[7]};
        *reinterpret_cast<float4*>(&rawd[(size_t)v * 8])     = o0;
        *reinterpret_cast<float4*>(&rawd[(size_t)v * 8 + 4]) = o1;
    }
}

// ---------------------------------------------------------------------------
// Layer-2 alpha + SAGPool score from rawd2 (NT x 8 dots) — R10-verified.
// ---------------------------------------------------------------------------
__device__ __forceinline__ float4 alpha_of(const float* __restrict__ rawd, int v, int j) {
    float4 o = {0.f, 0.5f, 0.f, 0.5f};
    if (j > 0) {
        const float* dv = &rawd[(size_t)v * 8];
        const float* dp = &rawd[(size_t)(v - 1) * 8];
        {
            const float ein = leaky(dp[0] + dv[2]), esf = leaky(dv[0] + dv[2]);
            const float m = fmaxf(ein, esf);
            const float win = expf(ein - m), wsf = expf(esf - m);
            const float den = win + wsf + 1e-16f;
            o.x = 0.5f * win / den; o.y = 0.5f * wsf / den;
        }
        {
            const float ein = leaky(dp[1] + dv[3]), esf = leaky(dv[1] + dv[3]);
            const float m = fmaxf(ein, esf);
            const float win = expf(ein - m), wsf = expf(esf - m);
            const float den = win + wsf + 1e-16f;
            o.z = 0.5f * win / den; o.w = 0.5f * wsf / den;
        }
    }
    return o;
}

__global__ __launch_bounds__(256)
void score_alpha(const float* __restrict__ rawd, const float* __restrict__ consts,
                 const float* __restrict__ pb, float* __restrict__ alph,
                 float* __restrict__ score) {
    const int v = blockIdx.x * 256 + threadIdx.x;
    if (v >= NT) return;
    const int j = v & (NNODE - 1);

    const float4 o = alpha_of(rawd, v, j);
    *reinterpret_cast<float4*>(&alph[(size_t)v * 4]) = o;

    const int vm1 = (j > 0) ? v - 1 : v;   // o.x=o.z=0 when j==0
    float s = consts[0] + pb[0];
    s += o.x * rawd[(size_t)vm1 * 8 + 4] + o.y * rawd[(size_t)v * 8 + 4];
    s += o.z * rawd[(size_t)vm1 * 8 + 5] + o.w * rawd[(size_t)v * 8 + 5];

    if (j > 0) {
        const float4 op = alpha_of(rawd, v - 1, j - 1);
        const int vm2 = (j > 1) ? v - 2 : v - 1;
        s += consts[1];
        s += op.x * rawd[(size_t)vm2 * 8 + 6] + op.y * rawd[(size_t)(v - 1) * 8 + 6];
        s += op.z * rawd[(size_t)vm2 * 8 + 7] + op.w * rawd[(size_t)(v - 1) * 8 + 7];
    }
    score[v] = s;
}

// ---------------------------------------------------------------------------
// Per-graph top-K + gated MIX-pool + mini-GEMM (pool@W2) + classifier.
// ---------------------------------------------------------------------------
__global__ __launch_bounds__(1024)
void topk_pool(const float* __restrict__ score, const float* __restrict__ h1,
               const float* __restrict__ alpha2, const float* __restrict__ W2,
               const float* __restrict__ b2, const float* __restrict__ cls_W,
               const float* __restrict__ cls_b, float* __restrict__ out) {
    __shared__ unsigned long long keys[NNODE];
    __shared__ float sc[NNODE];
    __shared__ float pmix[4][512];
    __shared__ float gpart[4];
    __shared__ float red[8];

    const int b = blockIdx.x;
    const int tid = threadIdx.x;

    for (int i = tid; i < NNODE; i += 1024) {
        float v = score[(size_t)b * NNODE + i];
        sc[i] = v;
        unsigned u = __float_as_uint(v);
        u = (u & 0x80000000u) ? ~u : (u | 0x80000000u);
        keys[i] = ((unsigned long long)(~u) << 32) | (unsigned)i;
    }
    __syncthreads();

    for (int k = 2; k <= NNODE; k <<= 1) {
        for (int jj = k >> 1; jj > 0; jj >>= 1) {
            int i = ((tid & ~(jj - 1)) << 1) | (tid & (jj - 1));
            int ixj = i | jj;
            unsigned long long a = keys[i], c = keys[ixj];
            bool up = ((i & k) == 0);
            if ((a > c) == up) { keys[i] = c; keys[ixj] = a; }
            __syncthreads();
        }
    }

    const int g = tid >> 8;
    const int c = tid & 255;
    float a0 = 0.f, a1 = 0.f, gs = 0.f;
    for (int kk = g; kk < KKEEP; kk += 4) {
        const int idx  = (int)(keys[kk] & 0xffffffffu);
        const float gate = tanhf(sc[idx]);
        const size_t gidx = (size_t)b * NNODE + idx;
        const size_t pidx = (idx == 0) ? gidx : gidx - 1;   // ain'=0 at j==0
        const float4 al = *reinterpret_cast<const float4*>(&alpha2[gidx * 4]);
        const float hv = h1[gidx * 256 + c];
        const float hp = h1[pidx * 256 + c];
        a0 += gate * (al.x * hp + al.y * hv);
        a1 += gate * (al.z * hp + al.w * hv);
        if (c == 0) gs += gate;
    }
    pmix[g][c]       = a0;
    pmix[g][256 + c] = a1;
    if (c == 0) gpart[g] = gs;
    __syncthreads();

    if (tid < 512) pmix[0][tid] += pmix[1][tid] + pmix[2][tid] + pmix[3][tid];
    __syncthreads();

    if (tid < 256) {
        const float G = gpart[0] + gpart[1] + gpart[2] + gpart[3];
        const int n = tid;
        float s = 0.f;
        for (int cc = 0; cc < 256; ++cc) {
            const float* wrow = &W2[(size_t)cc * 512];
            s += pmix[0][cc] * wrow[n] + pmix[0][256 + cc] * wrow[256 + n];
        }
        const float pooled = (s + G * b2[n]) * (1.f / (float)KKEEP);
        float p0 = pooled * cls_W[n * 2 + 0];
        float p1 = pooled * cls_W[n * 2 + 1];
#pragma unroll
        for (int off = 32; off; off >>= 1) {
            p0 += __shfl_down(p0, off);
            p1 += __shfl_down(p1, off);
        }
        if ((n & 63) == 0) {
            red[(n >> 6) * 2 + 0] = p0;
            red[(n >> 6) * 2 + 1] = p1;
        }
    }
    __syncthreads();
    if (tid == 0) {
        out[b * 2 + 0] = red[0] + red[2] + red[4] + red[6] + cls_b[0];
        out[b * 2 + 1] = red[1] + red[3] + red[5] + red[7] + cls_b[1];
    }
}

// ---------------------------------------------------------------------------

extern "C" void kernel_launch(void* const* d_in, const int* in_sizes, int n_in,
                              void* d_out, int out_size, void* d_ws, size_t ws_size,
                              hipStream_t stream) {
    const float* x        = (const float*)d_in[0];
    const float* W1       = (const float*)d_in[1];
    const float* att_src1 = (const float*)d_in[2];
    const float* att_dst1 = (const float*)d_in[3];
    const float* b1       = (const float*)d_in[4];
    const float* W2       = (const float*)d_in[5];
    const float* att_src2 = (const float*)d_in[6];
    const float* att_dst2 = (const float*)d_in[7];
    const float* b2       = (const float*)d_in[8];
    const float* pW_root  = (const float*)d_in[9];
    const float* pW_rel   = (const float*)d_in[10];
    const float* pb       = (const float*)d_in[11];
    const float* cls_W    = (const float*)d_in[12];
    const float* cls_b    = (const float*)d_in[13];
    float* out = (float*)d_out;

    // workspace (~150 MB):
    float* h1     = (float*)d_ws;               // NT*256 f32
    float* alpha1 = h1 + (size_t)NT * 256;      // NT*4
    float* rawd1  = alpha1 + (size_t)NT * 4;    // NT*4
    float* rawd2  = rawd1 + (size_t)NT * 4;     // NT*8
    float* alpha2 = rawd2 + (size_t)NT * 8;     // NT*4
    float* score  = alpha2 + (size_t)NT * 4;    // NT
    short* B1h    = (short*)(score + NT);       // 256*1024
    short* B1l    = B1h + 256 * 1024;
    float* wvec1  = (float*)(B1l + 256 * 1024); // 4*512
    float* wv2    = wvec1 + 4 * 512;            // 8*256
    float* consts = wv2 + 8 * 256;              // 2

    // ---- prep (2 launches)
    build_misc<<<17, 256, 0, stream>>>(W1, att_src1, att_dst1, W2, att_src2,
                                       att_dst2, pW_root, pW_rel, b2,
                                       wvec1, wv2, consts);
    build_B<<<(256 * 1024) / 256, 256, 0, stream>>>(W1, B1h, B1l, 512);

    // ---- layer 1: dots from x, alpha1, fused mix+GEMM -> h1
    dots_x<<<NT / 4, 256, 0, stream>>>(x, wvec1, rawd1);
    alpha_from_dots<<<NT / 256, 256, 0, stream>>>(rawd1, alpha1);
    gemm_fused<<<NT / GBM, 512, 131072, stream>>>(x, B1h, B1l, alpha1, b1, h1, 1024);

    // ---- per-node h1 dots (L3-resident), then layer-2 alpha + score (no GEMM)
    dots_h<<<NT / 4, 256, 0, stream>>>(h1, wv2, rawd2);
    score_alpha<<<NT / 256, 256, 0, stream>>>(rawd2, consts, pb, alpha2, score);

    // ---- SAGPool top-k + gated mix-pool + pool@W2 + classifier
    topk_pool<<<NGRAPH, 1024, 0, stream>>>(score, h1, alpha2, W2, b2, cls_W, cls_b, out);
}